// Round 14
// baseline (156.788 us; speedup 1.0000x reference)
//
#include <hip/hip_runtime.h>
#include <math.h>

#define CC 128
#define NN 4096   // 16*16*16
#define BB 2
#define NGROUPS 32
#define CPG 4
#define GSIZE (CPG*NN)          // 16384 elements per (b, group)
#define KSPLIT 16

typedef __attribute__((ext_vector_type(8))) __bf16 bf16x8;
typedef __attribute__((ext_vector_type(4))) float floatx4;

__device__ __forceinline__ unsigned short f2bf(float f) {
  union { float f; unsigned u; } v; v.f = f;
  unsigned r = v.u + 0x7fff + ((v.u >> 16) & 1);   // RNE
  return (unsigned short)(r >> 16);
}
__device__ __forceinline__ float bf2f(unsigned short u) {
  return __uint_as_float(((unsigned)u) << 16);
}

// Tiled layouts (per batch, NN*CC elements):
//  Q/K: elem(n,ch) at (n>>4)*2048 + (ch>>5)*512 + (n&15)*32 + (ch&31)
//  V:   elem(ch,m) at (m>>5)*4096 + (ch>>4)*512 + (ch&15)*32 + (m&31)
// A 64-col K tile = 4 n-tiles = 16 KB CONTIGUOUS; a 64-m V tile = 2 m-tiles = 16 KB
// CONTIGUOUS -> global_load_lds staging is a pure lane-linear copy.

// one wave stages 4 KB (4 chunks of 1 KB); w uniform-per-wave, lane per-lane
__device__ __forceinline__ void stage_tile(const unsigned short* __restrict__ gtile,
                                           unsigned short* ltile, int w, int lane) {
  #pragma unroll
  for (int j = 0; j < 4; j++) {
    int off = (w*4 + j) * 512;   // shorts
    __builtin_amdgcn_global_load_lds(
        (const __attribute__((address_space(1))) unsigned int*)(gtile + off + lane*8),
        (__attribute__((address_space(3))) unsigned int*)(ltile + off),
        16, 0, 0);
  }
}

// ---- stage 1 (320 blocks): 0-255 GN partial sums; 256-319 weight f32->bf16 ----
__global__ void gn_stats_kernel(const float* __restrict__ x, float2* __restrict__ stats,
                                const float* __restrict__ wq, const float* __restrict__ wk,
                                const float* __restrict__ wv, const float* __restrict__ wp,
                                unsigned short* __restrict__ wqb, unsigned short* __restrict__ wkb,
                                unsigned short* __restrict__ wvb, unsigned short* __restrict__ wpb) {
  int t = threadIdx.x;
  if (blockIdx.x < 256) {
    int bid = blockIdx.x;
    const float4* base = (const float4*)(x + (size_t)bid * 4096);
    float4 v = base[t];
    float s  = v.x + v.y + v.z + v.w;
    float ss = v.x*v.x + v.y*v.y + v.z*v.z + v.w*v.w;
    #pragma unroll
    for (int off = 1; off < 64; off <<= 1) {
      s  += __shfl_xor(s, off);
      ss += __shfl_xor(ss, off);
    }
    __shared__ float sred[4], ssred[4];
    if ((t & 63) == 0) { sred[t >> 6] = s; ssred[t >> 6] = ss; }
    __syncthreads();
    if (t == 0)
      stats[bid] = make_float2(sred[0]+sred[1]+sred[2]+sred[3],
                               ssred[0]+ssred[1]+ssred[2]+ssred[3]);
  } else {
    const float sc = 0.08838834764831845f;   // 128^-0.5, folded into wq
    int i = (blockIdx.x - 256) * 256 + t;    // float4 index; 4096 per weight
    int id = i >> 12, local = i & 4095;
    const float* src = id==0 ? wq : id==1 ? wk : id==2 ? wv : wp;
    unsigned short* dst = id==0 ? wqb : id==1 ? wkb : id==2 ? wvb : wpb;
    float s = (id == 0) ? sc : 1.0f;
    float4 v = ((const float4*)src)[local];
    unsigned p0 = (unsigned)f2bf(v.x*s) | ((unsigned)f2bf(v.y*s) << 16);
    unsigned p1 = (unsigned)f2bf(v.z*s) | ((unsigned)f2bf(v.w*s) << 16);
    ((uint2*)dst)[local] = make_uint2(p0, p1);
  }
}

// ---- fused q/k/v: one 16-row tile per block computes all three convs (A-frags
// loaded once, reused 3x). grid (NN/16, BB) = 512 blocks, 2/CU. ----
__global__ __launch_bounds__(256, 2) void qkv_kernel(
    const float* __restrict__ x, const float2* __restrict__ stats,
    const float* __restrict__ gamma, const float* __restrict__ beta,
    const unsigned short* __restrict__ wqb, const unsigned short* __restrict__ wkb,
    const unsigned short* __restrict__ wvb,
    const float* __restrict__ bq, const float* __restrict__ bk, const float* __restrict__ bv,
    unsigned short* __restrict__ q, unsigned short* __restrict__ k, unsigned short* __restrict__ v) {
  int b = blockIdx.y, n0 = blockIdx.x * 16;
  __shared__ unsigned short hs[16][130];   // normalized x tile, bf16 [n][c]
  __shared__ unsigned short vs[16][136];   // v transpose staging
  __shared__ float gm[NGROUPS], gr[NGROUPS], aa[CC], ab[CC];
  int t = threadIdx.x;
  if (t < NGROUPS) {
    float su = 0.f, ssq = 0.f;
    #pragma unroll
    for (int j = 0; j < 4; j++) {
      float2 p = stats[(b*NGROUPS + t)*4 + j];
      su += p.x; ssq += p.y;
    }
    float mean = su * (1.0f/GSIZE);
    float var  = ssq * (1.0f/GSIZE) - mean*mean;
    gm[t] = mean;
    gr[t] = rsqrtf(var + 1e-5f);
  }
  __syncthreads();
  if (t < CC) {
    int g = t >> 2;
    float a = gr[g] * gamma[t];
    aa[t] = a;
    ab[t] = beta[t] - gm[g] * a;
  }
  __syncthreads();
  // x tile: 16 rows x 128 ch = 512 float4 over 256 threads
  #pragma unroll
  for (int j = 0; j < 2; j++) {
    int idx = j*256 + t;
    int c = idx >> 2, n4 = idx & 3;
    float4 xv = *(const float4*)(x + ((size_t)b*CC + c)*NN + n0 + n4*4);
    float a = aa[c], bc = ab[c];
    hs[n4*4+0][c] = f2bf(a*xv.x + bc);
    hs[n4*4+1][c] = f2bf(a*xv.y + bc);
    hs[n4*4+2][c] = f2bf(a*xv.z + bc);
    hs[n4*4+3][c] = f2bf(a*xv.w + bc);
  }
  __syncthreads();
  int w = t >> 6, lane = t & 63, quad = lane >> 4, c = lane & 15;
  int o0 = w * 32;
  // A-fragments once, reused for q/k/v
  bf16x8 af[4];
  #pragma unroll
  for (int ks = 0; ks < 4; ks++)
    af[ks] = *(const bf16x8*)&hs[c][ks*32 + quad*8];
  floatx4 aq[2], ak[2], av[2];
  #pragma unroll
  for (int ct = 0; ct < 2; ct++) {
    aq[ct] = (floatx4){0.f,0.f,0.f,0.f};
    ak[ct] = (floatx4){0.f,0.f,0.f,0.f};
    av[ct] = (floatx4){0.f,0.f,0.f,0.f};
  }
  #pragma unroll
  for (int ks = 0; ks < 4; ks++) {
    #pragma unroll
    for (int ct = 0; ct < 2; ct++) {
      size_t woff = (size_t)(o0 + ct*16 + c)*CC + ks*32 + quad*8;
      bf16x8 bq8 = *(const bf16x8*)(wqb + woff);
      bf16x8 bk8 = *(const bf16x8*)(wkb + woff);
      bf16x8 bv8 = *(const bf16x8*)(wvb + woff);
      aq[ct] = __builtin_amdgcn_mfma_f32_16x16x32_bf16(af[ks], bq8, aq[ct], 0, 0, 0);
      ak[ct] = __builtin_amdgcn_mfma_f32_16x16x32_bf16(af[ks], bk8, ak[ct], 0, 0, 0);
      av[ct] = __builtin_amdgcn_mfma_f32_16x16x32_bf16(af[ks], bv8, av[ct], 0, 0, 0);
    }
  }
  // q,k tiled stores: this block covers exactly n-tile blockIdx.x
  {
    const float sc = 0.08838834764831845f;
    size_t base = (size_t)b*NN*CC + (size_t)blockIdx.x*2048 + w*512;
    #pragma unroll
    for (int ct = 0; ct < 2; ct++) {
      float bqi = bq[o0 + ct*16 + c] * sc;
      float bki = bk[o0 + ct*16 + c];
      #pragma unroll
      for (int r = 0; r < 4; r++) {
        int idx = (quad*4 + r)*32 + ct*16 + c;
        q[base + idx] = f2bf(aq[ct][r] + bqi);
        k[base + idx] = f2bf(ak[ct][r] + bki);
      }
    }
  }
  // v transpose via LDS then tiled V store
  #pragma unroll
  for (int ct = 0; ct < 2; ct++) {
    float bvi = bv[o0 + ct*16 + c];
    #pragma unroll
    for (int r = 0; r < 4; r++)
      vs[quad*4 + r][o0 + ct*16 + c] = f2bf(av[ct][r] + bvi);
  }
  __syncthreads();
  {
    // elem(ch,m): (m>>5)*4096 + (ch>>4)*512 + (ch&15)*32 + (m&31); our m = n0..n0+15
    int ch = t >> 1, part = t & 1;      // 8 m per thread
    int mbase = (n0 & 16) + part*8;
    unsigned pk[4];
    #pragma unroll
    for (int j = 0; j < 4; j++) {
      unsigned lo = vs[part*8 + j*2    ][ch];
      unsigned hi = vs[part*8 + j*2 + 1][ch];
      pk[j] = lo | (hi << 16);
    }
    *(uint4*)(v + (size_t)b*NN*CC + ((size_t)(n0 >> 5))*4096 + (ch >> 4)*512
              + (ch & 15)*32 + mbase) = make_uint4(pk[0], pk[1], pk[2], pk[3]);
  }
}

// ---- MFMA flash attention: 256 q-rows/block (4 waves x 64), LDS-shared K/V.
// S^T trick (A=K, B=Q) keeps P row-major per lane; 64 rows/wave means each K/V
// LDS fragment read feeds 4 MFMAs (was 2). ct-outer QK loop caps live ST regs.
// LDS 68.9 KB -> 2 blocks/CU; grid (16, KSPLIT=16, B) = 512 blocks. ----
__global__ __launch_bounds__(256, 2) void attn_kernel(
    const unsigned short* __restrict__ qm,  // tiled QK layout, q-scale folded
    const unsigned short* __restrict__ km,  // tiled QK layout
    const unsigned short* __restrict__ vm,  // tiled V layout
    unsigned short* __restrict__ Opart,     // [KSPLIT][B][N][C] bf16, unnormalized
    float* __restrict__ lpart) {            // [KSPLIT][B][N] f32
  int b    = blockIdx.z;
  int kh   = blockIdx.y;
  int t    = threadIdx.x;
  int w    = t >> 6, lane = t & 63, quad = lane >> 4, c = lane & 15;

  __shared__ unsigned short Kbuf[8192];      // 16 KB: 4 n-tiles x 2048 shorts
  __shared__ unsigned short Vbuf[8192];      // 16 KB: 2 m-tiles x 4096 shorts
  __shared__ unsigned short Pl[4][64][72];   // wave-private P, [q_row][k]

  int fragoff = c*32 + quad*8;

  // Q fragments: this wave's 64 rows = n-tiles blockIdx.x*16 + w*4 + rt
  bf16x8 qa[4][4];
  const unsigned short* qbase = qm + (size_t)b*NN*CC + ((size_t)(blockIdx.x*16 + w*4))*2048;
  #pragma unroll
  for (int rt = 0; rt < 4; rt++)
    #pragma unroll
    for (int ks = 0; ks < 4; ks++)
      qa[rt][ks] = *(const bf16x8*)(qbase + rt*2048 + ks*512 + fragoff);

  floatx4 O[4][8];
  #pragma unroll
  for (int rt = 0; rt < 4; rt++)
    #pragma unroll
    for (int ct = 0; ct < 8; ct++) O[rt][ct] = (floatx4){0.f,0.f,0.f,0.f};
  float lsum[4] = {0.f, 0.f, 0.f, 0.f};   // in-lane: row rt*16+c

  const unsigned short* kt0 = km + (size_t)b*NN*CC + (size_t)kh*(NN/KSPLIT)*CC;
  const unsigned short* vt0 = vm + (size_t)b*NN*CC + (size_t)kh*(NN/KSPLIT)*CC;

  const int ITERS = NN/KSPLIT/64;   // 4

  stage_tile(kt0, Kbuf, w, lane);
  stage_tile(vt0, Vbuf, w, lane);
  __syncthreads();

  for (int it = 0; it < ITERS; it++) {
    // ---- S^T = K Q^T, ct-outer (live ST = 4 floatx4); exp/pack per ct ----
    #pragma unroll
    for (int ct = 0; ct < 4; ct++) {
      floatx4 ST[4];
      #pragma unroll
      for (int rt = 0; rt < 4; rt++) ST[rt] = (floatx4){0.f,0.f,0.f,0.f};
      #pragma unroll
      for (int ks = 0; ks < 4; ks++) {
        bf16x8 kf = *(const bf16x8*)&Kbuf[ct*2048 + ks*512 + fragoff];
        #pragma unroll
        for (int rt = 0; rt < 4; rt++)
          ST[rt] = __builtin_amdgcn_mfma_f32_16x16x32_bf16(kf, qa[rt][ks], ST[rt], 0, 0, 0);
      }
      #pragma unroll
      for (int rt = 0; rt < 4; rt++) {
        float e0 = __expf(ST[rt][0]);
        float e1 = __expf(ST[rt][1]);
        float e2 = __expf(ST[rt][2]);
        float e3 = __expf(ST[rt][3]);
        lsum[rt] += (e0 + e1) + (e2 + e3);
        unsigned p01 = (__float_as_uint(e1) & 0xffff0000u) | (__float_as_uint(e0) >> 16);
        unsigned p23 = (__float_as_uint(e3) & 0xffff0000u) | (__float_as_uint(e2) >> 16);
        *(uint2*)&Pl[w][rt*16 + c][ct*16 + quad*4] = make_uint2(p01, p23);
      }
    }
    __syncthreads();   // all waves done with Kbuf (QK); V staging (prev iter) drained
    if (it+1 < ITERS) stage_tile(kt0 + (size_t)(it+1)*8192, Kbuf, w, lane);  // overlaps PV
    // ---- O += P V from LDS: each vf feeds 4 MFMAs ----
    #pragma unroll
    for (int ks2 = 0; ks2 < 2; ks2++) {
      bf16x8 pa[4];
      #pragma unroll
      for (int rt = 0; rt < 4; rt++)
        pa[rt] = *(const bf16x8*)(&Pl[w][rt*16 + c][ks2*32 + quad*8]);
      #pragma unroll
      for (int ct = 0; ct < 8; ct++) {
        bf16x8 vf = *(const bf16x8*)&Vbuf[ks2*4096 + ct*512 + fragoff];
        #pragma unroll
        for (int rt = 0; rt < 4; rt++)
          O[rt][ct] = __builtin_amdgcn_mfma_f32_16x16x32_bf16(pa[rt], vf, O[rt][ct], 0, 0, 0);
      }
    }
    __syncthreads();   // all waves done with Vbuf; K staging drained
    if (it+1 < ITERS) stage_tile(vt0 + (size_t)(it+1)*8192, Vbuf, w, lane);  // overlaps next QK
  }

  // ---- epilogue: wave-private; lsum butterfly over quads; packed O stores ----
  size_t nbase = (size_t)(kh*BB + b)*NN + blockIdx.x*256 + w*64;
  #pragma unroll
  for (int rt = 0; rt < 4; rt++) {
    float vsum = lsum[rt];
    vsum += __shfl_xor(vsum, 16);
    vsum += __shfl_xor(vsum, 32);
    if (lane < 16) lpart[nbase + rt*16 + lane] = vsum;
  }
  bool odd = (c & 1);
  int colpair = (c & ~1);
  #pragma unroll
  for (int rt = 0; rt < 4; rt++) {
    #pragma unroll
    for (int ct = 0; ct < 8; ct++) {
      unsigned u0 = f2bf(O[rt][ct][0]);
      unsigned u1 = f2bf(O[rt][ct][1]);
      unsigned u2 = f2bf(O[rt][ct][2]);
      unsigned u3 = f2bf(O[rt][ct][3]);
      // lane-pair exchange: even lane ends with rows {0,2}'s col pair, odd rows {1,3}
      unsigned s01 = odd ? u0 : u1;
      unsigned g01 = __shfl_xor((int)s01, 1);
      unsigned p0 = odd ? (g01 | (u1 << 16)) : (u0 | (g01 << 16));
      unsigned s23 = odd ? u2 : u3;
      unsigned g23 = __shfl_xor((int)s23, 1);
      unsigned p1 = odd ? (g23 | (u3 << 16)) : (u2 | (g23 << 16));
      int rowA = rt*16 + quad*4 + (odd ? 1 : 0);
      int rowB = rt*16 + quad*4 + (odd ? 3 : 2);
      *(unsigned*)(Opart + (nbase + rowA)*CC + ct*16 + colpair) = p0;
      *(unsigned*)(Opart + (nbase + rowB)*CC + ct*16 + colpair) = p1;
    }
  }
}

// ---- combine 16 partials + normalize + proj (MFMA) + bias + residual -> out [B,C,N]
//      16-row tiles: grid (NN/16, BB) = 512 blocks, 2/CU ----
__global__ __launch_bounds__(256, 2) void combine_kernel(
    const unsigned short* __restrict__ Opart, const float* __restrict__ lpart,
    const unsigned short* __restrict__ wpb, const float* __restrict__ bp,
    const float* __restrict__ x, float* __restrict__ out) {
  int b = blockIdx.y, n0 = blockIdx.x * 16;
  int t = threadIdx.x;
  __shared__ unsigned short hs[16][130];   // normalized attn output, bf16
  __shared__ float ps[16][132];            // proj result staging
  __shared__ float linv[16];
  if (t < 16) {
    float l = 0.f;
    #pragma unroll
    for (int kh = 0; kh < KSPLIT; kh++)
      l += lpart[((size_t)(kh*BB + b))*NN + n0 + t];
    linv[t] = 1.f / l;
  }
  __syncthreads();
  {
    int n = t >> 4, ch0 = (t & 15) * 8;   // 16 n x 16 chunks of 8 ch
    float acc[8];
    #pragma unroll
    for (int j = 0; j < 8; j++) acc[j] = 0.f;
    #pragma unroll
    for (int kh = 0; kh < KSPLIT; kh++) {
      uint4 a = *(const uint4*)(Opart + ((size_t)(kh*BB + b)*NN + n0 + n)*CC + ch0);
      unsigned uu[4] = {a.x, a.y, a.z, a.w};
      #pragma unroll
      for (int j = 0; j < 4; j++) {
        acc[j*2    ] += bf2f((unsigned short)(uu[j] & 0xffff));
        acc[j*2 + 1] += bf2f((unsigned short)(uu[j] >> 16));
      }
    }
    float li = linv[n];
    #pragma unroll
    for (int j = 0; j < 8; j++) hs[n][ch0 + j] = f2bf(acc[j] * li);
  }
  __syncthreads();
  int w = t >> 6, lane = t & 63, quad = lane >> 4, c = lane & 15;
  int o0 = w * 32;
  floatx4 acc[2];
  #pragma unroll
  for (int ct = 0; ct < 2; ct++) acc[ct] = (floatx4){0.f,0.f,0.f,0.f};
  #pragma unroll
  for (int ks = 0; ks < 4; ks++) {
    bf16x8 af = *(const bf16x8*)&hs[c][ks*32 + quad*8];
    #pragma unroll
    for (int ct = 0; ct < 2; ct++) {
      bf16x8 bfr = *(const bf16x8*)(wpb + (size_t)(o0 + ct*16 + c)*CC + ks*32 + quad*8);
      acc[ct] = __builtin_amdgcn_mfma_f32_16x16x32_bf16(af, bfr, acc[ct], 0, 0, 0);
    }
  }
  #pragma unroll
  for (int ct = 0; ct < 2; ct++)
    #pragma unroll
    for (int r = 0; r < 4; r++)
      ps[quad*4 + r][o0 + ct*16 + c] = acc[ct][r];
  __syncthreads();
  int o = t >> 1, nh = (t & 1) * 8;
  float bi = bp[o];
  const float* xr = x + ((size_t)b*CC + o)*NN + n0 + nh;
  float* orow = out + ((size_t)b*CC + o)*NN + n0 + nh;
  #pragma unroll
  for (int j4 = 0; j4 < 2; j4++) {
    float4 xv = ((const float4*)xr)[j4];
    float4 ov;
    ov.x = xv.x + ps[nh + j4*4 + 0][o] + bi;
    ov.y = xv.y + ps[nh + j4*4 + 1][o] + bi;
    ov.z = xv.z + ps[nh + j4*4 + 2][o] + bi;
    ov.w = xv.w + ps[nh + j4*4 + 3][o] + bi;
    ((float4*)orow)[j4] = ov;
  }
}

extern "C" void kernel_launch(void* const* d_in, const int* in_sizes, int n_in,
                              void* d_out, int out_size, void* d_ws, size_t ws_size,
                              hipStream_t stream) {
  const float* x    = (const float*)d_in[0];
  const float* gn_w = (const float*)d_in[1];
  const float* gn_b = (const float*)d_in[2];
  const float* wq   = (const float*)d_in[3];
  const float* bq   = (const float*)d_in[4];
  const float* wk   = (const float*)d_in[5];
  const float* bk   = (const float*)d_in[6];
  const float* wv   = (const float*)d_in[7];
  const float* bv   = (const float*)d_in[8];
  const float* wp   = (const float*)d_in[9];
  const float* bp   = (const float*)d_in[10];
  float* out = (float*)d_out;

  char* ws = (char*)d_ws;
  float2*         stats = (float2*)(ws);                       // 2048 B
  unsigned short* wqb   = (unsigned short*)(ws + 8192);        // 32 KiB each
  unsigned short* wkb   = (unsigned short*)(ws + 8192 + 32768);
  unsigned short* wvb   = (unsigned short*)(ws + 8192 + 65536);
  unsigned short* wpb   = (unsigned short*)(ws + 8192 + 98304);
  unsigned short* qb    = (unsigned short*)(ws + 262144);                  // 2 MiB
  unsigned short* kb    = (unsigned short*)(ws + 262144 + 2097152);        // 2 MiB
  unsigned short* vb    = (unsigned short*)(ws + 262144 + 2*2097152);      // 2 MiB
  unsigned short* Opart = (unsigned short*)(ws + 6553600);                 // 32 MiB
  float*          lpart = (float*)(ws + 6553600 + 33554432);               // 512 KiB

  gn_stats_kernel<<<dim3(320), 256, 0, stream>>>(x, stats, wq, wk, wv, wp,
                                                 wqb, wkb, wvb, wpb);
  qkv_kernel     <<<dim3(NN/16, BB), 256, 0, stream>>>(x, stats, gn_w, gn_b,
                                                       wqb, wkb, wvb, bq, bk, bv,
                                                       qb, kb, vb);
  attn_kernel    <<<dim3(NN/256, KSPLIT, BB), 256, 0, stream>>>(qb, kb, vb, Opart, lpart);
  combine_kernel <<<dim3(NN/16, BB), 256, 0, stream>>>(Opart, lpart, wpb, bp, x, out);
}

// Round 15
// 115.372 us; speedup vs baseline: 1.3590x; 1.3590x over previous
//
#include <hip/hip_runtime.h>
#include <math.h>

#define CC 128
#define NN 4096   // 16*16*16
#define BB 2
#define NGROUPS 32
#define CPG 4
#define GSIZE (CPG*NN)          // 16384 elements per (b, group)
#define KSPLIT 8

typedef __attribute__((ext_vector_type(8))) __bf16 bf16x8;
typedef __attribute__((ext_vector_type(4))) float floatx4;

__device__ __forceinline__ unsigned short f2bf(float f) {
  union { float f; unsigned u; } v; v.f = f;
  unsigned r = v.u + 0x7fff + ((v.u >> 16) & 1);   // RNE
  return (unsigned short)(r >> 16);
}
__device__ __forceinline__ float bf2f(unsigned short u) {
  return __uint_as_float(((unsigned)u) << 16);
}

// Tiled layouts (per batch, NN*CC elements):
//  Q/K: elem(n,ch) at (n>>4)*2048 + (ch>>5)*512 + (n&15)*32 + (ch&31)
//  V:   elem(ch,m) at (m>>5)*4096 + (ch>>4)*512 + (ch&15)*32 + (m&31)
// A 64-col K tile = 4 n-tiles = 16 KB CONTIGUOUS; a 64-m V tile = 2 m-tiles = 16 KB
// CONTIGUOUS -> global_load_lds staging is a pure lane-linear copy.

// one wave stages 4 KB (4 chunks of 1 KB); w uniform-per-wave, lane per-lane
__device__ __forceinline__ void stage_tile(const unsigned short* __restrict__ gtile,
                                           unsigned short* ltile, int w, int lane) {
  #pragma unroll
  for (int j = 0; j < 4; j++) {
    int off = (w*4 + j) * 512;   // shorts
    __builtin_amdgcn_global_load_lds(
        (const __attribute__((address_space(1))) unsigned int*)(gtile + off + lane*8),
        (__attribute__((address_space(3))) unsigned int*)(ltile + off),
        16, 0, 0);
  }
}

// ---- stage 1 (320 blocks): 0-255 GN partial sums; 256-319 weight f32->bf16 ----
__global__ void gn_stats_kernel(const float* __restrict__ x, float2* __restrict__ stats,
                                const float* __restrict__ wq, const float* __restrict__ wk,
                                const float* __restrict__ wv, const float* __restrict__ wp,
                                unsigned short* __restrict__ wqb, unsigned short* __restrict__ wkb,
                                unsigned short* __restrict__ wvb, unsigned short* __restrict__ wpb) {
  int t = threadIdx.x;
  if (blockIdx.x < 256) {
    int bid = blockIdx.x;
    const float4* base = (const float4*)(x + (size_t)bid * 4096);
    float4 v = base[t];
    float s  = v.x + v.y + v.z + v.w;
    float ss = v.x*v.x + v.y*v.y + v.z*v.z + v.w*v.w;
    #pragma unroll
    for (int off = 1; off < 64; off <<= 1) {
      s  += __shfl_xor(s, off);
      ss += __shfl_xor(ss, off);
    }
    __shared__ float sred[4], ssred[4];
    if ((t & 63) == 0) { sred[t >> 6] = s; ssred[t >> 6] = ss; }
    __syncthreads();
    if (t == 0)
      stats[bid] = make_float2(sred[0]+sred[1]+sred[2]+sred[3],
                               ssred[0]+ssred[1]+ssred[2]+ssred[3]);
  } else {
    const float sc = 0.08838834764831845f;   // 128^-0.5, folded into wq
    int i = (blockIdx.x - 256) * 256 + t;    // float4 index; 4096 per weight
    int id = i >> 12, local = i & 4095;
    const float* src = id==0 ? wq : id==1 ? wk : id==2 ? wv : wp;
    unsigned short* dst = id==0 ? wqb : id==1 ? wkb : id==2 ? wvb : wpb;
    float s = (id == 0) ? sc : 1.0f;
    float4 v = ((const float4*)src)[local];
    unsigned p0 = (unsigned)f2bf(v.x*s) | ((unsigned)f2bf(v.y*s) << 16);
    unsigned p1 = (unsigned)f2bf(v.z*s) | ((unsigned)f2bf(v.w*s) << 16);
    ((uint2*)dst)[local] = make_uint2(p0, p1);
  }
}

// ---- fused q/k/v: one 16-row tile per block computes all three convs (A-frags
// loaded once, reused 3x). grid (NN/16, BB) = 512 blocks, 2/CU. ----
__global__ __launch_bounds__(256, 2) void qkv_kernel(
    const float* __restrict__ x, const float2* __restrict__ stats,
    const float* __restrict__ gamma, const float* __restrict__ beta,
    const unsigned short* __restrict__ wqb, const unsigned short* __restrict__ wkb,
    const unsigned short* __restrict__ wvb,
    const float* __restrict__ bq, const float* __restrict__ bk, const float* __restrict__ bv,
    unsigned short* __restrict__ q, unsigned short* __restrict__ k, unsigned short* __restrict__ v) {
  int b = blockIdx.y, n0 = blockIdx.x * 16;
  __shared__ unsigned short hs[16][130];   // normalized x tile, bf16 [n][c]
  __shared__ unsigned short vs[16][136];   // v transpose staging
  __shared__ float gm[NGROUPS], gr[NGROUPS], aa[CC], ab[CC];
  int t = threadIdx.x;
  if (t < NGROUPS) {
    float su = 0.f, ssq = 0.f;
    #pragma unroll
    for (int j = 0; j < 4; j++) {
      float2 p = stats[(b*NGROUPS + t)*4 + j];
      su += p.x; ssq += p.y;
    }
    float mean = su * (1.0f/GSIZE);
    float var  = ssq * (1.0f/GSIZE) - mean*mean;
    gm[t] = mean;
    gr[t] = rsqrtf(var + 1e-5f);
  }
  __syncthreads();
  if (t < CC) {
    int g = t >> 2;
    float a = gr[g] * gamma[t];
    aa[t] = a;
    ab[t] = beta[t] - gm[g] * a;
  }
  __syncthreads();
  // x tile: 16 rows x 128 ch = 512 float4 over 256 threads
  #pragma unroll
  for (int j = 0; j < 2; j++) {
    int idx = j*256 + t;
    int c = idx >> 2, n4 = idx & 3;
    float4 xv = *(const float4*)(x + ((size_t)b*CC + c)*NN + n0 + n4*4);
    float a = aa[c], bc = ab[c];
    hs[n4*4+0][c] = f2bf(a*xv.x + bc);
    hs[n4*4+1][c] = f2bf(a*xv.y + bc);
    hs[n4*4+2][c] = f2bf(a*xv.z + bc);
    hs[n4*4+3][c] = f2bf(a*xv.w + bc);
  }
  __syncthreads();
  int w = t >> 6, lane = t & 63, quad = lane >> 4, c = lane & 15;
  int o0 = w * 32;
  // A-fragments once, reused for q/k/v
  bf16x8 af[4];
  #pragma unroll
  for (int ks = 0; ks < 4; ks++)
    af[ks] = *(const bf16x8*)&hs[c][ks*32 + quad*8];
  floatx4 aq[2], ak[2], av[2];
  #pragma unroll
  for (int ct = 0; ct < 2; ct++) {
    aq[ct] = (floatx4){0.f,0.f,0.f,0.f};
    ak[ct] = (floatx4){0.f,0.f,0.f,0.f};
    av[ct] = (floatx4){0.f,0.f,0.f,0.f};
  }
  #pragma unroll
  for (int ks = 0; ks < 4; ks++) {
    #pragma unroll
    for (int ct = 0; ct < 2; ct++) {
      size_t woff = (size_t)(o0 + ct*16 + c)*CC + ks*32 + quad*8;
      bf16x8 bq8 = *(const bf16x8*)(wqb + woff);
      bf16x8 bk8 = *(const bf16x8*)(wkb + woff);
      bf16x8 bv8 = *(const bf16x8*)(wvb + woff);
      aq[ct] = __builtin_amdgcn_mfma_f32_16x16x32_bf16(af[ks], bq8, aq[ct], 0, 0, 0);
      ak[ct] = __builtin_amdgcn_mfma_f32_16x16x32_bf16(af[ks], bk8, ak[ct], 0, 0, 0);
      av[ct] = __builtin_amdgcn_mfma_f32_16x16x32_bf16(af[ks], bv8, av[ct], 0, 0, 0);
    }
  }
  // q,k tiled stores: this block covers exactly n-tile blockIdx.x
  {
    const float sc = 0.08838834764831845f;
    size_t base = (size_t)b*NN*CC + (size_t)blockIdx.x*2048 + w*512;
    #pragma unroll
    for (int ct = 0; ct < 2; ct++) {
      float bqi = bq[o0 + ct*16 + c] * sc;
      float bki = bk[o0 + ct*16 + c];
      #pragma unroll
      for (int r = 0; r < 4; r++) {
        int idx = (quad*4 + r)*32 + ct*16 + c;
        q[base + idx] = f2bf(aq[ct][r] + bqi);
        k[base + idx] = f2bf(ak[ct][r] + bki);
      }
    }
  }
  // v transpose via LDS then tiled V store
  #pragma unroll
  for (int ct = 0; ct < 2; ct++) {
    float bvi = bv[o0 + ct*16 + c];
    #pragma unroll
    for (int r = 0; r < 4; r++)
      vs[quad*4 + r][o0 + ct*16 + c] = f2bf(av[ct][r] + bvi);
  }
  __syncthreads();
  {
    // elem(ch,m): (m>>5)*4096 + (ch>>4)*512 + (ch&15)*32 + (m&31); our m = n0..n0+15
    int ch = t >> 1, part = t & 1;      // 8 m per thread
    int mbase = (n0 & 16) + part*8;
    unsigned pk[4];
    #pragma unroll
    for (int j = 0; j < 4; j++) {
      unsigned lo = vs[part*8 + j*2    ][ch];
      unsigned hi = vs[part*8 + j*2 + 1][ch];
      pk[j] = lo | (hi << 16);
    }
    *(uint4*)(v + (size_t)b*NN*CC + ((size_t)(n0 >> 5))*4096 + (ch >> 4)*512
              + (ch & 15)*32 + mbase) = make_uint4(pk[0], pk[1], pk[2], pk[3]);
  }
}

// ---- MFMA flash attention: 128 q-rows/block (4 waves x 32), LDS-shared K/V.
// QK computed TRANSPOSED (A=K, B=Q -> S^T): each lane then owns one q-row with
// k-cols row-major in registers, so the P->LDS transpose collapses to 8 b64
// writes/iter (was 32 b32 writes + 16 shfls). lsum is in-lane. LDS 50.4 KB,
// grid (32, KSPLIT=8, B) = 512 blocks, 2/CU. 32 rows/wave = the no-spill sweet
// spot (r14: 64 rows/wave spilled; r9: 16 rows/wave under-amortized barriers). ----
__global__ __launch_bounds__(256, 2) void attn_kernel(
    const unsigned short* __restrict__ qm,  // tiled QK layout, q-scale folded
    const unsigned short* __restrict__ km,  // tiled QK layout
    const unsigned short* __restrict__ vm,  // tiled V layout
    unsigned short* __restrict__ Opart,     // [KSPLIT][B][N][C] bf16, unnormalized
    float* __restrict__ lpart) {            // [KSPLIT][B][N] f32
  int b    = blockIdx.z;
  int kh   = blockIdx.y;
  int t    = threadIdx.x;
  int w    = t >> 6, lane = t & 63, quad = lane >> 4, c = lane & 15;

  __shared__ unsigned short Kbuf[8192];      // 16 KB: 4 n-tiles x 2048 shorts
  __shared__ unsigned short Vbuf[8192];      // 16 KB: 2 m-tiles x 4096 shorts
  __shared__ unsigned short Pl[4][32][72];   // wave-private P, [q_row][k]

  int fragoff = c*32 + quad*8;

  bf16x8 qa[2][4];
  const unsigned short* qbase = qm + (size_t)b*NN*CC + ((size_t)(blockIdx.x*8 + w*2))*2048;
  #pragma unroll
  for (int rt = 0; rt < 2; rt++)
    #pragma unroll
    for (int ks = 0; ks < 4; ks++)
      qa[rt][ks] = *(const bf16x8*)(qbase + rt*2048 + ks*512 + fragoff);

  floatx4 O[2][8];
  #pragma unroll
  for (int rt = 0; rt < 2; rt++)
    #pragma unroll
    for (int ct = 0; ct < 8; ct++) O[rt][ct] = (floatx4){0.f,0.f,0.f,0.f};
  float lsum[2] = {0.f, 0.f};   // in-lane: row rt*16+c, this lane's k-col subset

  const unsigned short* kt0 = km + (size_t)b*NN*CC + (size_t)kh*(NN/KSPLIT)*CC;
  const unsigned short* vt0 = vm + (size_t)b*NN*CC + (size_t)kh*(NN/KSPLIT)*CC;

  const int ITERS = NN/KSPLIT/64;   // 8

  stage_tile(kt0, Kbuf, w, lane);
  stage_tile(vt0, Vbuf, w, lane);
  __syncthreads();

  for (int it = 0; it < ITERS; it++) {
    // ---- S^T = K Q^T from LDS: lane (c,quad) reg r = S[q_row=rt*16+c][ct*16+quad*4+r]
    floatx4 ST[2][4];
    #pragma unroll
    for (int rt = 0; rt < 2; rt++)
      #pragma unroll
      for (int ct = 0; ct < 4; ct++) ST[rt][ct] = (floatx4){0.f,0.f,0.f,0.f};
    #pragma unroll
    for (int ks = 0; ks < 4; ks++) {
      #pragma unroll
      for (int ct = 0; ct < 4; ct++) {
        bf16x8 kf = *(const bf16x8*)&Kbuf[ct*2048 + ks*512 + fragoff];
        ST[0][ct] = __builtin_amdgcn_mfma_f32_16x16x32_bf16(kf, qa[0][ks], ST[0][ct], 0, 0, 0);
        ST[1][ct] = __builtin_amdgcn_mfma_f32_16x16x32_bf16(kf, qa[1][ks], ST[1][ct], 0, 0, 0);
      }
    }
    // ---- P = exp(S^T); in-lane lsum; in-lane pack -> one b64 write per (rt,ct) ----
    #pragma unroll
    for (int rt = 0; rt < 2; rt++) {
      #pragma unroll
      for (int ct = 0; ct < 4; ct++) {
        float e0 = __expf(ST[rt][ct][0]);
        float e1 = __expf(ST[rt][ct][1]);
        float e2 = __expf(ST[rt][ct][2]);
        float e3 = __expf(ST[rt][ct][3]);
        lsum[rt] += (e0 + e1) + (e2 + e3);
        unsigned p01 = (__float_as_uint(e1) & 0xffff0000u) | (__float_as_uint(e0) >> 16);
        unsigned p23 = (__float_as_uint(e3) & 0xffff0000u) | (__float_as_uint(e2) >> 16);
        *(uint2*)&Pl[w][rt*16 + c][ct*16 + quad*4] = make_uint2(p01, p23);
      }
    }
    __syncthreads();   // all waves done with Kbuf (QK); V staging (prev iter) drained
    if (it+1 < ITERS) stage_tile(kt0 + (size_t)(it+1)*8192, Kbuf, w, lane);  // overlaps PV
    // ---- O += P V from LDS ----
    #pragma unroll
    for (int ks2 = 0; ks2 < 2; ks2++) {
      bf16x8 pa0 = *(const bf16x8*)(&Pl[w][c     ][ks2*32 + quad*8]);
      bf16x8 pa1 = *(const bf16x8*)(&Pl[w][16 + c][ks2*32 + quad*8]);
      #pragma unroll
      for (int ct = 0; ct < 8; ct++) {
        bf16x8 vf = *(const bf16x8*)&Vbuf[ks2*4096 + ct*512 + fragoff];
        O[0][ct] = __builtin_amdgcn_mfma_f32_16x16x32_bf16(pa0, vf, O[0][ct], 0, 0, 0);
        O[1][ct] = __builtin_amdgcn_mfma_f32_16x16x32_bf16(pa1, vf, O[1][ct], 0, 0, 0);
      }
    }
    __syncthreads();   // all waves done with Vbuf; K staging drained
    if (it+1 < ITERS) stage_tile(vt0 + (size_t)(it+1)*8192, Vbuf, w, lane);  // overlaps next QK
  }

  // ---- epilogue: wave-private; lsum butterfly over quads; packed O stores ----
  size_t nbase = (size_t)(kh*BB + b)*NN + blockIdx.x*128 + w*32;
  #pragma unroll
  for (int rt = 0; rt < 2; rt++) {
    float vsum = lsum[rt];
    vsum += __shfl_xor(vsum, 16);
    vsum += __shfl_xor(vsum, 32);
    if (lane < 16) lpart[nbase + rt*16 + lane] = vsum;
  }
  bool odd = (c & 1);
  int colpair = (c & ~1);
  #pragma unroll
  for (int rt = 0; rt < 2; rt++) {
    #pragma unroll
    for (int ct = 0; ct < 8; ct++) {
      unsigned u0 = f2bf(O[rt][ct][0]);
      unsigned u1 = f2bf(O[rt][ct][1]);
      unsigned u2 = f2bf(O[rt][ct][2]);
      unsigned u3 = f2bf(O[rt][ct][3]);
      // lane-pair exchange: even lane ends with rows {0,2}'s col pair, odd rows {1,3}
      unsigned s01 = odd ? u0 : u1;
      unsigned g01 = __shfl_xor((int)s01, 1);
      unsigned p0 = odd ? (g01 | (u1 << 16)) : (u0 | (g01 << 16));
      unsigned s23 = odd ? u2 : u3;
      unsigned g23 = __shfl_xor((int)s23, 1);
      unsigned p1 = odd ? (g23 | (u3 << 16)) : (u2 | (g23 << 16));
      int rowA = rt*16 + quad*4 + (odd ? 1 : 0);
      int rowB = rt*16 + quad*4 + (odd ? 3 : 2);
      *(unsigned*)(Opart + (nbase + rowA)*CC + ct*16 + colpair) = p0;
      *(unsigned*)(Opart + (nbase + rowB)*CC + ct*16 + colpair) = p1;
    }
  }
}

// ---- combine 8 partials + normalize + proj (MFMA) + bias + residual -> out [B,C,N]
//      16-row tiles: grid (NN/16, BB) = 512 blocks, 2/CU ----
__global__ __launch_bounds__(256, 2) void combine_kernel(
    const unsigned short* __restrict__ Opart, const float* __restrict__ lpart,
    const unsigned short* __restrict__ wpb, const float* __restrict__ bp,
    const float* __restrict__ x, float* __restrict__ out) {
  int b = blockIdx.y, n0 = blockIdx.x * 16;
  int t = threadIdx.x;
  __shared__ unsigned short hs[16][130];   // normalized attn output, bf16
  __shared__ float ps[16][132];            // proj result staging
  __shared__ float linv[16];
  if (t < 16) {
    float l = 0.f;
    #pragma unroll
    for (int kh = 0; kh < KSPLIT; kh++)
      l += lpart[((size_t)(kh*BB + b))*NN + n0 + t];
    linv[t] = 1.f / l;
  }
  __syncthreads();
  {
    int n = t >> 4, ch0 = (t & 15) * 8;   // 16 n x 16 chunks of 8 ch
    float acc[8];
    #pragma unroll
    for (int j = 0; j < 8; j++) acc[j] = 0.f;
    #pragma unroll
    for (int kh = 0; kh < KSPLIT; kh++) {
      uint4 a = *(const uint4*)(Opart + ((size_t)(kh*BB + b)*NN + n0 + n)*CC + ch0);
      unsigned uu[4] = {a.x, a.y, a.z, a.w};
      #pragma unroll
      for (int j = 0; j < 4; j++) {
        acc[j*2    ] += bf2f((unsigned short)(uu[j] & 0xffff));
        acc[j*2 + 1] += bf2f((unsigned short)(uu[j] >> 16));
      }
    }
    float li = linv[n];
    #pragma unroll
    for (int j = 0; j < 8; j++) hs[n][ch0 + j] = f2bf(acc[j] * li);
  }
  __syncthreads();
  int w = t >> 6, lane = t & 63, quad = lane >> 4, c = lane & 15;
  int o0 = w * 32;
  floatx4 acc[2];
  #pragma unroll
  for (int ct = 0; ct < 2; ct++) acc[ct] = (floatx4){0.f,0.f,0.f,0.f};
  #pragma unroll
  for (int ks = 0; ks < 4; ks++) {
    bf16x8 af = *(const bf16x8*)&hs[c][ks*32 + quad*8];
    #pragma unroll
    for (int ct = 0; ct < 2; ct++) {
      bf16x8 bfr = *(const bf16x8*)(wpb + (size_t)(o0 + ct*16 + c)*CC + ks*32 + quad*8);
      acc[ct] = __builtin_amdgcn_mfma_f32_16x16x32_bf16(af, bfr, acc[ct], 0, 0, 0);
    }
  }
  #pragma unroll
  for (int ct = 0; ct < 2; ct++)
    #pragma unroll
    for (int r = 0; r < 4; r++)
      ps[quad*4 + r][o0 + ct*16 + c] = acc[ct][r];
  __syncthreads();
  int o = t >> 1, nh = (t & 1) * 8;
  float bi = bp[o];
  const float* xr = x + ((size_t)b*CC + o)*NN + n0 + nh;
  float* orow = out + ((size_t)b*CC + o)*NN + n0 + nh;
  #pragma unroll
  for (int j4 = 0; j4 < 2; j4++) {
    float4 xv = ((const float4*)xr)[j4];
    float4 ov;
    ov.x = xv.x + ps[nh + j4*4 + 0][o] + bi;
    ov.y = xv.y + ps[nh + j4*4 + 1][o] + bi;
    ov.z = xv.z + ps[nh + j4*4 + 2][o] + bi;
    ov.w = xv.w + ps[nh + j4*4 + 3][o] + bi;
    ((float4*)orow)[j4] = ov;
  }
}

extern "C" void kernel_launch(void* const* d_in, const int* in_sizes, int n_in,
                              void* d_out, int out_size, void* d_ws, size_t ws_size,
                              hipStream_t stream) {
  const float* x    = (const float*)d_in[0];
  const float* gn_w = (const float*)d_in[1];
  const float* gn_b = (const float*)d_in[2];
  const float* wq   = (const float*)d_in[3];
  const float* bq   = (const float*)d_in[4];
  const float* wk   = (const float*)d_in[5];
  const float* bk   = (const float*)d_in[6];
  const float* wv   = (const float*)d_in[7];
  const float* bv   = (const float*)d_in[8];
  const float* wp   = (const float*)d_in[9];
  const float* bp   = (const float*)d_in[10];
  float* out = (float*)d_out;

  char* ws = (char*)d_ws;
  float2*         stats = (float2*)(ws);                       // 2048 B
  unsigned short* wqb   = (unsigned short*)(ws + 8192);        // 32 KiB each
  unsigned short* wkb   = (unsigned short*)(ws + 8192 + 32768);
  unsigned short* wvb   = (unsigned short*)(ws + 8192 + 65536);
  unsigned short* wpb   = (unsigned short*)(ws + 8192 + 98304);
  unsigned short* qb    = (unsigned short*)(ws + 262144);                  // 2 MiB
  unsigned short* kb    = (unsigned short*)(ws + 262144 + 2097152);        // 2 MiB
  unsigned short* vb    = (unsigned short*)(ws + 262144 + 2*2097152);      // 2 MiB
  unsigned short* Opart = (unsigned short*)(ws + 6553600);                 // 16 MiB
  float*          lpart = (float*)(ws + 6553600 + 16777216);               // 256 KiB

  gn_stats_kernel<<<dim3(320), 256, 0, stream>>>(x, stats, wq, wk, wv, wp,
                                                 wqb, wkb, wvb, wpb);
  qkv_kernel     <<<dim3(NN/16, BB), 256, 0, stream>>>(x, stats, gn_w, gn_b,
                                                       wqb, wkb, wvb, bq, bk, bv,
                                                       qb, kb, vb);
  attn_kernel    <<<dim3(NN/128, KSPLIT, BB), 256, 0, stream>>>(qb, kb, vb, Opart, lpart);
  combine_kernel <<<dim3(NN/16, BB), 256, 0, stream>>>(Opart, lpart, wpb, bp, x, out);
}